// Round 1
// baseline (50.518 us; speedup 1.0000x reference)
//
#include <hip/hip_runtime.h>

// Shapes fixed by the reference: B=1, S=4096, H=32, D=128, M=4096.
#define HH 32
#define DD 128
#define MM 4096
// floats per token row = H*D = 4096  -> 1024 float4s
#define ROW_F4 1024
#define D_F4   (DD / 4)     // 32 float4 per (h, m) row
#define F4_PER_H 32

__global__ __launch_bounds__(256)
void teleport_quant_kernel(const float* __restrict__ kin,
                           const float* __restrict__ vin,
                           const float* __restrict__ unc,
                           const float* __restrict__ kc_in,
                           const float* __restrict__ vc_in,
                           const float* __restrict__ ksc_in,
                           const float* __restrict__ vsc_in,
                           const int*   __restrict__ cur_pos,
                           float* __restrict__ kc_out,
                           float* __restrict__ vc_out,
                           float* __restrict__ ksc_out,
                           float* __restrict__ vsc_out,
                           int S)
{
    const int m = blockIdx.x;      // output cache position 0..M-1
    const int t = threadIdx.x;     // 0..255

    // Inverse circular map: which token (if any) last wrote position m.
    int cp  = *cur_pos;
    int cpm = cp % MM; if (cpm < 0) cpm += MM;
    int s0  = m - cpm; if (s0 < 0) s0 += MM;
    const int s = (s0 < S) ? (s0 + MM * ((S - 1 - s0) / MM)) : -1;

    if (s < 0) {
        // Position untouched this step: copy old cache + scales through.
        const float4* kci = reinterpret_cast<const float4*>(kc_in);
        const float4* vci = reinterpret_cast<const float4*>(vc_in);
        float4* kco = reinterpret_cast<float4*>(kc_out);
        float4* vco = reinterpret_cast<float4*>(vc_out);
        #pragma unroll
        for (int c = 0; c < 4; ++c) {
            int f4 = c * 256 + t;                       // 0..1023
            int h  = f4 >> 5;                           // f4 / F4_PER_H
            int o  = h * (MM * D_F4) + m * D_F4 + (f4 & (F4_PER_H - 1));
            kco[o] = kci[o];
            vco[o] = vci[o];
        }
        if (t < HH)            ksc_out[t * MM + m]        = ksc_in[t * MM + m];
        else if (t < 2 * HH)   vsc_out[(t - HH) * MM + m] = vsc_in[(t - HH) * MM + m];
        return;
    }

    // ---- quantize token s into cache position m ----
    const float4* k4 = reinterpret_cast<const float4*>(kin) + (size_t)s * ROW_F4;
    const float4* v4 = reinterpret_cast<const float4*>(vin) + (size_t)s * ROW_F4;

    float4 ka[4], va[4];
    float amk = 0.0f, amv = 0.0f;
    #pragma unroll
    for (int c = 0; c < 4; ++c) {
        int f4 = c * 256 + t;
        ka[c] = k4[f4];
        va[c] = v4[f4];
        amk = fmaxf(amk, fmaxf(fmaxf(fabsf(ka[c].x), fabsf(ka[c].y)),
                               fmaxf(fabsf(ka[c].z), fabsf(ka[c].w))));
        amv = fmaxf(amv, fmaxf(fmaxf(fabsf(va[c].x), fabsf(va[c].y)),
                               fmaxf(fabsf(va[c].z), fabsf(va[c].w))));
    }

    // wave64 butterfly reduce (both values)
    #pragma unroll
    for (int off = 32; off > 0; off >>= 1) {
        amk = fmaxf(amk, __shfl_xor(amk, off, 64));
        amv = fmaxf(amv, __shfl_xor(amv, off, 64));
    }
    __shared__ float rk[4], rv[4];
    const int wid = t >> 6;
    if ((t & 63) == 0) { rk[wid] = amk; rv[wid] = amv; }
    __syncthreads();
    amk = fmaxf(fmaxf(rk[0], rk[1]), fmaxf(rk[2], rk[3]));
    amv = fmaxf(fmaxf(rv[0], rv[1]), fmaxf(rv[2], rv[3]));

    const float u   = unc[s];
    const float div = (u > 0.1f) ? 224.0f : 448.0f;
    const float ks  = fmaxf(amk / div, 1e-8f);
    const float vs  = fmaxf(amv / div, 1e-8f);
    const float rks = 1.0f / ks;   // correctly-rounded; <=1ulp vs per-elem div
    const float rvs = 1.0f / vs;

    float4* kco = reinterpret_cast<float4*>(kc_out);
    float4* vco = reinterpret_cast<float4*>(vc_out);
    #pragma unroll
    for (int c = 0; c < 4; ++c) {
        int f4 = c * 256 + t;
        int h  = f4 >> 5;
        int o  = h * (MM * D_F4) + m * D_F4 + (f4 & (F4_PER_H - 1));
        float4 qk, qv;
        qk.x = fminf(fmaxf(ka[c].x * rks, -448.0f), 448.0f);
        qk.y = fminf(fmaxf(ka[c].y * rks, -448.0f), 448.0f);
        qk.z = fminf(fmaxf(ka[c].z * rks, -448.0f), 448.0f);
        qk.w = fminf(fmaxf(ka[c].w * rks, -448.0f), 448.0f);
        qv.x = fminf(fmaxf(va[c].x * rvs, -448.0f), 448.0f);
        qv.y = fminf(fmaxf(va[c].y * rvs, -448.0f), 448.0f);
        qv.z = fminf(fmaxf(va[c].z * rvs, -448.0f), 448.0f);
        qv.w = fminf(fmaxf(va[c].w * rvs, -448.0f), 448.0f);
        kco[o] = qk;
        vco[o] = qv;
    }

    if (t < HH)            ksc_out[t * MM + m]        = ks;
    else if (t < 2 * HH)   vsc_out[(t - HH) * MM + m] = vs;
}

extern "C" void kernel_launch(void* const* d_in, const int* in_sizes, int n_in,
                              void* d_out, int out_size, void* d_ws, size_t ws_size,
                              hipStream_t stream) {
    const float* kin = (const float*)d_in[0];
    const float* vin = (const float*)d_in[1];
    const float* unc = (const float*)d_in[2];
    const float* kc  = (const float*)d_in[3];
    const float* vc  = (const float*)d_in[4];
    const float* ksc = (const float*)d_in[5];
    const float* vsc = (const float*)d_in[6];
    const int*   cp  = (const int*)d_in[7];
    const int S = in_sizes[2];   // B*S with B=1

    float* out  = (float*)d_out;
    float* kco  = out;
    float* vco  = kco + (size_t)HH * MM * DD;
    float* ksco = vco + (size_t)HH * MM * DD;
    float* vsco = ksco + (size_t)HH * MM;

    teleport_quant_kernel<<<MM, 256, 0, stream>>>(
        kin, vin, unc, kc, vc, ksc, vsc, cp, kco, vco, ksco, vsco, S);
}